// Round 6
// baseline (981.471 us; speedup 1.0000x reference)
//
#include <hip/hip_runtime.h>
#include <hip/hip_bf16.h>

#define NNODES 100000
#define NEDGES 1600000
#define NRELS 16
#define NBASES 8
#define DFEAT 128
#define NCLS 40
#define MAXDEG 64
#define KTOT 1152   // NBASES*128 + 128 (root)
#define CHUNK 25088 // 196*128: A-chunk = 57.8 MB -> Infinity-Cache-resident

typedef __attribute__((ext_vector_type(8))) short bf16x8v;
typedef __attribute__((ext_vector_type(4))) float f32x4v;
typedef __attribute__((ext_vector_type(2))) float f32x2v;

// Fused fp32->bf16 convert + per-row int8 quant (wave per row).
__global__ __launch_bounds__(256)
void k_cvq(const float* __restrict__ x, __hip_bfloat16* __restrict__ xb,
           short* __restrict__ q8, float* __restrict__ qs, int nrows)
{
    int wave = threadIdx.x >> 6, lane = threadIdx.x & 63;
    int v = blockIdx.x * 4 + wave;
    if (v >= nrows) return;
    float2 xv = ((const float2*)x)[(size_t)v * 64 + lane];
    __hip_bfloat162 bv;
    bv.x = __float2bfloat16(xv.x);
    bv.y = __float2bfloat16(xv.y);
    ((__hip_bfloat162*)xb)[(size_t)v * 64 + lane] = bv;
    float m = fmaxf(fabsf(xv.x), fabsf(xv.y));
#pragma unroll
    for (int o = 32; o; o >>= 1) m = fmaxf(m, __shfl_xor(m, o));
    float inv = (m > 0.f) ? 127.f / m : 0.f;
    int qx = (int)rintf(xv.x * inv), qy = (int)rintf(xv.y * inv);
    q8[(size_t)v * 64 + lane] = (short)((qx & 0xff) | (qy << 8));
    if (lane == 0) qs[v] = m * (1.f / 127.f);
}

// One atomic per edge: degD slot-claim doubles as ELL write index.
__global__ __launch_bounds__(256)
void k_build(const int* __restrict__ esrc, const int* __restrict__ edst,
             const int* __restrict__ etyp,
             unsigned* __restrict__ degD, unsigned* __restrict__ ell)
{
    int e = blockIdx.x * 256 + threadIdx.x;
    if (e >= NEDGES) return;
    int d = edst[e], t = etyp[e], s = esrc[e];
    unsigned slot = atomicAdd(&degD[d], 1u);
    if (slot < MAXDEG) ell[(size_t)d * MAXDEG + slot] = ((unsigned)s << 4) | (unsigned)t;
}

// Per-row int8 quantization of node features (layers 1,2).
__global__ __launch_bounds__(256)
void k_quant(const __hip_bfloat16* __restrict__ h,
             short* __restrict__ q8, float* __restrict__ qs, int nrows)
{
    int wave = threadIdx.x >> 6, lane = threadIdx.x & 63;
    int v = blockIdx.x * 4 + wave;
    if (v >= nrows) return;
    __hip_bfloat162 xv = ((const __hip_bfloat162*)h)[(size_t)v * 64 + lane];
    float xl = __bfloat162float(xv.x), xh = __bfloat162float(xv.y);
    float m = fmaxf(fabsf(xl), fabsf(xh));
#pragma unroll
    for (int o = 32; o; o >>= 1) m = fmaxf(m, __shfl_xor(m, o));
    float inv = (m > 0.f) ? 127.f / m : 0.f;
    int qx = (int)rintf(xl * inv), qy = (int)rintf(xh * inv);
    q8[(size_t)v * 64 + lane] = (short)((qx & 0xff) | (qy << 8));
    if (lane == 0) qs[v] = m * (1.f / 127.f);
}

// One wave per node. Lane e owns edge e: folded coefficients
// c[b] = comp[t_e,b] * (1/deg(dst,t_e)) * qs[src_e] + src idx written to LDS
// once per node; edge loop reads them at wave-uniform addresses
// (ds_read_b128 broadcast, conflict-free). Packed f32x2 FMAs.
__global__ __launch_bounds__(256)
void k_agg(const short* __restrict__ q8, const float* __restrict__ qs,
           const __hip_bfloat16* __restrict__ hin,
           const unsigned* __restrict__ ell,
           const unsigned* __restrict__ degD,
           const float* __restrict__ comp,
           __hip_bfloat16* __restrict__ A,
           int r0, int rows)
{
    __shared__ float compS[NRELS * NBASES];
    __shared__ __align__(16) float cS[4][MAXDEG][8];
    __shared__ unsigned sS[4][MAXDEG];
    if (threadIdx.x < NRELS * NBASES) compS[threadIdx.x] = comp[threadIdx.x];
    __syncthreads();
    int wave = threadIdx.x >> 6, lane = threadIdx.x & 63;
    int rl = blockIdx.x * 4 + wave;
    if (rl >= rows) return;
    int v = r0 + rl;
    int ne = (int)degD[v]; if (ne > MAXDEG) ne = MAXDEG;
    const unsigned* erow = ell + (size_t)v * MAXDEG;
    unsigned packed = (lane < ne) ? erow[lane] : 0u;
    unsigned t_l = packed & 15u;
    int s_l = (lane < ne) ? (int)(packed >> 4) : 0;
    unsigned long long m = __ballot(lane < ne);
#pragma unroll
    for (int b = 0; b < 4; b++) {
        unsigned long long bb = __ballot((t_l >> b) & 1u);
        m &= ((t_l >> b) & 1u) ? bb : ~bb;
    }
    int cnt = __popcll(m); if (cnt < 1) cnt = 1;
    float w_l = (lane < ne) ? (qs[s_l] / (float)cnt) : 0.f;   // 0 => branchless pad
    f32x4v c0, c1;
#pragma unroll
    for (int b = 0; b < 4; b++) c0[b] = compS[t_l * NBASES + b] * w_l;
#pragma unroll
    for (int b = 0; b < 4; b++) c1[b] = compS[t_l * NBASES + 4 + b] * w_l;
    *(f32x4v*)&cS[wave][lane][0] = c0;          // once per node
    *(f32x4v*)&cS[wave][lane][4] = c1;
    sS[wave][lane] = (unsigned)s_l;
    // same-wave RAW on LDS: compiler's lgkmcnt ordering suffices, no barrier

    f32x2v acc[NBASES];
#pragma unroll
    for (int b = 0; b < NBASES; b++) acc[b] = (f32x2v){0.f, 0.f};

    for (int e0 = 0; e0 < ne; e0 += 8) {
        unsigned sj[8]; short qv[8];
#pragma unroll
        for (int j = 0; j < 8; j++) sj[j] = sS[wave][e0 + j];   // uniform broadcast
#pragma unroll
        for (int j = 0; j < 8; j++)                              // 8 gathers in flight
            qv[j] = q8[(size_t)sj[j] * 64 + lane];
#pragma unroll
        for (int j = 0; j < 8; j++) {
            f32x4v ca = *(const f32x4v*)&cS[wave][e0 + j][0];
            f32x4v cb = *(const f32x4v*)&cS[wave][e0 + j][4];
            f32x2v f2;
            f2.x = (float)(char)(qv[j] & 0xff);
            f2.y = (float)(qv[j] >> 8);
            acc[0] += ca[0] * f2;  acc[1] += ca[1] * f2;
            acc[2] += ca[2] * f2;  acc[3] += ca[3] * f2;
            acc[4] += cb[0] * f2;  acc[5] += cb[1] * f2;
            acc[6] += cb[2] * f2;  acc[7] += cb[3] * f2;
        }
    }
    const __hip_bfloat162* h2p = (const __hip_bfloat162*)hin;
    __hip_bfloat162* A2 = (__hip_bfloat162*)(A + (size_t)rl * KTOT);
#pragma unroll
    for (int b = 0; b < NBASES; b++) {
        __hip_bfloat162 o;
        o.x = __float2bfloat16(acc[b].x);
        o.y = __float2bfloat16(acc[b].y);
        A2[b * 64 + lane] = o;
    }
    A2[512 + lane] = h2p[(size_t)v * 64 + lane];   // root part: own features (bf16)
}

// WT[o][k] (B^T, K-contiguous).
__global__ __launch_bounds__(256)
void k_w(const float* __restrict__ bases, const float* __restrict__ root,
         __hip_bfloat16* __restrict__ WT, int dout, int npad)
{
    int idx = blockIdx.x * 256 + threadIdx.x;
    int total = npad * KTOT;
    if (idx >= total) return;
    int o = idx / KTOT, k = idx - o * KTOT;
    float v = 0.f;
    if (o < dout) v = (k < 1024) ? bases[k * dout + o] : root[(k - 1024) * dout + o];
    WT[idx] = __float2bfloat16(v);
}

// C[M,NT] = A[M,K] * WT[NT,K]^T. 128x{128|64} tile, BK=32, 4 waves,
// mfma_f32_16x16x32_bf16, global_load_lds (width 16) staging.
template<int NT, bool RELU, bool FINAL>
__global__ __launch_bounds__(256)
void k_gemm(const __hip_bfloat16* __restrict__ A,
            const __hip_bfloat16* __restrict__ WT,
            const float* __restrict__ bias,
            void* __restrict__ outp,
            int r0, int rows, int dout)
{
    constexpr int WM = (NT == 128) ? 2 : 4;
    constexpr int WN = 4 / WM;
    constexpr int MT = 128 / (16 * WM);
    constexpr int NTW = NT / (16 * WN);
    __shared__ __align__(16) __hip_bfloat16 As[128 * 32];
    __shared__ __align__(16) __hip_bfloat16 Bs[NT * 32];
    int tid = threadIdx.x;
    int wave = tid >> 6, lane = tid & 63;
    int wm = wave % WM, wn = wave / WM;
    int bm = blockIdx.x * 128;
    int lm = lane & 15, lq = lane >> 4;
    f32x4v zero = {0.f, 0.f, 0.f, 0.f};
    f32x4v acc[MT][NTW];
#pragma unroll
    for (int a = 0; a < MT; a++)
#pragma unroll
        for (int b = 0; b < NTW; b++) acc[a][b] = zero;

    for (int k0 = 0; k0 < KTOT; k0 += 32) {
#pragma unroll
        for (int j = 0; j < 2; j++) {
            int slot = tid + 256 * j;
            int row = slot >> 2, kc = (slot & 3) << 3;
            __builtin_amdgcn_global_load_lds(
                (const __attribute__((address_space(1))) void*)
                    &A[(size_t)(bm + row) * KTOT + k0 + kc],
                (__attribute__((address_space(3))) void*)&As[slot * 8],
                16, 0, 0);
        }
#pragma unroll
        for (int j = 0; j < NT / 64; j++) {
            int slot = tid + 256 * j;
            int row = slot >> 2, kc = (slot & 3) << 3;
            __builtin_amdgcn_global_load_lds(
                (const __attribute__((address_space(1))) void*)
                    &WT[(size_t)row * KTOT + k0 + kc],
                (__attribute__((address_space(3))) void*)&Bs[slot * 8],
                16, 0, 0);
        }
        __syncthreads();
        bf16x8v af[MT], bfr[NTW];
#pragma unroll
        for (int mt = 0; mt < MT; mt++)
            af[mt] = *(const bf16x8v*)&As[(wm * (16 * MT) + mt * 16 + lm) * 32 + lq * 8];
#pragma unroll
        for (int nt = 0; nt < NTW; nt++)
            bfr[nt] = *(const bf16x8v*)&Bs[(wn * (16 * NTW) + nt * 16 + lm) * 32 + lq * 8];
#pragma unroll
        for (int mt = 0; mt < MT; mt++)
#pragma unroll
            for (int nt = 0; nt < NTW; nt++)
                acc[mt][nt] = __builtin_amdgcn_mfma_f32_16x16x32_bf16(
                    af[mt], bfr[nt], acc[mt][nt], 0, 0, 0);
        __syncthreads();
    }
#pragma unroll
    for (int mt = 0; mt < MT; mt++) {
        int rbase = bm + wm * (16 * MT) + mt * 16 + lq * 4;
#pragma unroll
        for (int nt = 0; nt < NTW; nt++) {
            int col = wn * (16 * NTW) + nt * 16 + lm;
#pragma unroll
            for (int i = 0; i < 4; i++) {
                int rl = rbase + i;
                if (rl < rows && col < dout) {
                    float v = acc[mt][nt][i] + bias[col];
                    if (RELU) v = fmaxf(v, 0.f);
                    if (FINAL)
                        ((float*)outp)[(size_t)(r0 + rl) * NCLS + col] = v;
                    else
                        ((__hip_bfloat16*)outp)[(size_t)(r0 + rl) * DFEAT + col] =
                            __float2bfloat16(v);
                }
            }
        }
    }
}

extern "C" void kernel_launch(void* const* d_in, const int* in_sizes, int n_in,
                              void* d_out, int out_size, void* d_ws, size_t ws_size,
                              hipStream_t stream)
{
    const float* x  = (const float*)d_in[0];
    const int* esrc = (const int*)d_in[1];
    const int* edst = (const int*)d_in[2];
    const int* etyp = (const int*)d_in[3];
    const float* basesA[3] = {(const float*)d_in[4], (const float*)d_in[8], (const float*)d_in[12]};
    const float* compA[3]  = {(const float*)d_in[5], (const float*)d_in[9], (const float*)d_in[13]};
    const float* rootA[3]  = {(const float*)d_in[6], (const float*)d_in[10], (const float*)d_in[14]};
    const float* biasA[3]  = {(const float*)d_in[7], (const float*)d_in[11], (const float*)d_in[15]};

    size_t off = 0;
    char* base = (char*)d_ws;
    auto carve = [&](size_t bytes) -> void* {
        void* r = base + off;
        off += (bytes + 255) & ~(size_t)255;
        return r;
    };
    __hip_bfloat16* xb = (__hip_bfloat16*)carve((size_t)NNODES * DFEAT * 2);
    __hip_bfloat16* h1 = (__hip_bfloat16*)carve((size_t)NNODES * DFEAT * 2);
    __hip_bfloat16* WT = (__hip_bfloat16*)carve((size_t)128 * KTOT * 2);
    unsigned* ell  = (unsigned*)carve((size_t)NNODES * MAXDEG * 4);
    unsigned* degD = (unsigned*)carve((size_t)NNODES * 4);
    short* q8  = (short*)carve((size_t)NNODES * 64 * 2);
    float* qsc = (float*)carve((size_t)NNODES * 4);
    __hip_bfloat16* h2 = xb;   // xb dead after layer 1 -> alias

    if (ws_size <= off) return;
    size_t arows = (ws_size - off) / ((size_t)KTOT * 2);
    if (arows > CHUNK) arows = CHUNK;          // L3-resident A chunk
    int chunk = (int)(arows & ~(size_t)127);
    if (chunk < 128) return;
    __hip_bfloat16* A = (__hip_bfloat16*)(base + off);

    hipMemsetAsync(degD, 0, (size_t)NNODES * 4, stream);
    k_cvq<<<(NNODES + 3) / 4, 256, 0, stream>>>(x, xb, q8, qsc, NNODES);
    k_build<<<(NEDGES + 255) / 256, 256, 0, stream>>>(esrc, edst, etyp, degD, ell);

    const __hip_bfloat16* hin = xb;
    __hip_bfloat16* houts[2] = {h1, h2};
    for (int l = 0; l < 3; l++) {
        int dout = (l == 2) ? NCLS : DFEAT;
        int npad = (l == 2) ? 64 : 128;
        if (l > 0)   // layer 0's q8/qs came fused from k_cvq
            k_quant<<<(NNODES + 3) / 4, 256, 0, stream>>>(hin, q8, qsc, NNODES);
        k_w<<<(npad * KTOT + 255) / 256, 256, 0, stream>>>(basesA[l], rootA[l], WT, dout, npad);
        for (int r0 = 0; r0 < NNODES; r0 += chunk) {
            int rows = NNODES - r0; if (rows > chunk) rows = chunk;
            k_agg<<<(rows + 3) / 4, 256, 0, stream>>>(q8, qsc, hin, ell, degD, compA[l], A, r0, rows);
            int gm = (rows + 127) / 128;
            if (l < 2)
                k_gemm<128, true, false><<<gm, 256, 0, stream>>>(A, WT, biasA[l], houts[l], r0, rows, dout);
            else
                k_gemm<64, false, true><<<gm, 256, 0, stream>>>(A, WT, biasA[l], d_out, r0, rows, dout);
        }
        if (l < 2) hin = houts[l];
    }
}

// Round 8
// 778.832 us; speedup vs baseline: 1.2602x; 1.2602x over previous
//
#include <hip/hip_runtime.h>
#include <hip/hip_bf16.h>

#define NNODES 100000
#define NEDGES 1600000
#define NRELS 16
#define NBASES 8
#define DFEAT 128
#define NCLS 40
#define MAXDEG 64
#define KTOT 1152   // NBASES*128 + 128 (root)

typedef __attribute__((ext_vector_type(8))) short bf16x8v;
typedef __attribute__((ext_vector_type(4))) float f32x4v;
typedef __attribute__((ext_vector_type(2))) float f32x2v;

struct __align__(8) bf16x4s { __hip_bfloat162 lo, hi; };

// Fused fp32->bf16 convert + per-row int8 quant (wave per row).
__global__ __launch_bounds__(256)
void k_cvq(const float* __restrict__ x, __hip_bfloat16* __restrict__ xb,
           short* __restrict__ q8, float* __restrict__ qs, int nrows)
{
    int wave = threadIdx.x >> 6, lane = threadIdx.x & 63;
    int v = blockIdx.x * 4 + wave;
    if (v >= nrows) return;
    float2 xv = ((const float2*)x)[(size_t)v * 64 + lane];
    __hip_bfloat162 bv;
    bv.x = __float2bfloat16(xv.x);
    bv.y = __float2bfloat16(xv.y);
    ((__hip_bfloat162*)xb)[(size_t)v * 64 + lane] = bv;
    float m = fmaxf(fabsf(xv.x), fabsf(xv.y));
#pragma unroll
    for (int o = 32; o; o >>= 1) m = fmaxf(m, __shfl_xor(m, o));
    float inv = (m > 0.f) ? 127.f / m : 0.f;
    int qx = (int)rintf(xv.x * inv), qy = (int)rintf(xv.y * inv);
    q8[(size_t)v * 64 + lane] = (short)((qx & 0xff) | (qy << 8));
    if (lane == 0) qs[v] = m * (1.f / 127.f);
}

// One atomic per edge: degD slot-claim doubles as ELL write index.
__global__ __launch_bounds__(256)
void k_build(const int* __restrict__ esrc, const int* __restrict__ edst,
             const int* __restrict__ etyp,
             unsigned* __restrict__ degD, unsigned* __restrict__ ell)
{
    int e = blockIdx.x * 256 + threadIdx.x;
    if (e >= NEDGES) return;
    int d = edst[e], t = etyp[e], s = esrc[e];
    unsigned slot = atomicAdd(&degD[d], 1u);
    if (slot < MAXDEG) ell[(size_t)d * MAXDEG + slot] = ((unsigned)s << 4) | (unsigned)t;
}

// Per-row int8 quantization of node features (layers 1,2).
__global__ __launch_bounds__(256)
void k_quant(const __hip_bfloat16* __restrict__ h,
             short* __restrict__ q8, float* __restrict__ qs, int nrows)
{
    int wave = threadIdx.x >> 6, lane = threadIdx.x & 63;
    int v = blockIdx.x * 4 + wave;
    if (v >= nrows) return;
    __hip_bfloat162 xv = ((const __hip_bfloat162*)h)[(size_t)v * 64 + lane];
    float xl = __bfloat162float(xv.x), xh = __bfloat162float(xv.y);
    float m = fmaxf(fabsf(xl), fabsf(xh));
#pragma unroll
    for (int o = 32; o; o >>= 1) m = fmaxf(m, __shfl_xor(m, o));
    float inv = (m > 0.f) ? 127.f / m : 0.f;
    int qx = (int)rintf(xl * inv), qy = (int)rintf(xh * inv);
    q8[(size_t)v * 64 + lane] = (short)((qx & 0xff) | (qy << 8));
    if (lane == 0) qs[v] = m * (1.f / 127.f);
}

// TWO nodes per wave (one per 32-lane half): each gather instruction fetches
// 2 edges x 128 B (4 cache lines vs 2) and the pipeline is 16 deep -> 2x the
// line-request rate of the 1-node/wave version. Lane hl owns channels
// 4hl..4hl+3 (one dword of the int8 row). Folded coefficients
// c[b]=comp[t,b]*(1/deg(dst,t))*qs[src] go through LDS once per node and are
// read back at per-half uniform addresses (2-addr broadcast = free).
// Per-(node,type) degree via per-half-wave LDS histogram (same-wave order).
__global__ __launch_bounds__(256)
void k_agg(const short* __restrict__ q8, const float* __restrict__ qs,
           const __hip_bfloat16* __restrict__ hin,
           const unsigned* __restrict__ ell,
           const unsigned* __restrict__ degD,
           const float* __restrict__ comp,
           __hip_bfloat16* __restrict__ A,
           int r0, int rows)
{
    __shared__ float compS[NRELS * NBASES];
    __shared__ __align__(16) float cS[8][MAXDEG][8];   // [node][slot][basis] 16 KB
    __shared__ unsigned sS[8][MAXDEG];                 // 2 KB
    __shared__ unsigned histS[8][NRELS];               // 512 B
    if (threadIdx.x < NRELS * NBASES) compS[threadIdx.x] = comp[threadIdx.x];
    __syncthreads();

    int wave = threadIdx.x >> 6, lane = threadIdx.x & 63;
    int half = lane >> 5, hl = lane & 31;
    int node = wave * 2 + half;                        // 0..7 within block
    int rl = blockIdx.x * 8 + node;
    bool alive = (rl < rows);
    int v = alive ? (r0 + rl) : 0;
    int ne = alive ? (int)degD[v] : 0; if (ne > MAXDEG) ne = MAXDEG;

    if (alive) {
        const unsigned* erow = ell + (size_t)v * MAXDEG;
        unsigned p0 = (hl < ne) ? erow[hl] : 0u;
        unsigned p1 = (hl + 32 < ne) ? erow[hl + 32] : 0u;
        // per-(node,type) histogram in LDS (all DS ops same-wave -> ordered)
        if (hl < NRELS) histS[node][hl] = 0u;
        if (hl < ne)      atomicAdd(&histS[node][p0 & 15u], 1u);
        if (hl + 32 < ne) atomicAdd(&histS[node][p1 & 15u], 1u);
        // fold coefficients for both owned slots
#pragma unroll
        for (int r = 0; r < 2; r++) {
            unsigned p = r ? p1 : p0;
            int slot = hl + 32 * r;
            bool val = (slot < ne);
            unsigned t = p & 15u;
            int s = val ? (int)(p >> 4) : 0;
            unsigned cnt = val ? histS[node][t] : 1u;
            if (cnt < 1u) cnt = 1u;
            float w = val ? (qs[s] / (float)cnt) : 0.f;
            f32x4v c0, c1;
#pragma unroll
            for (int b = 0; b < 4; b++) c0[b] = compS[t * NBASES + b] * w;
#pragma unroll
            for (int b = 0; b < 4; b++) c1[b] = compS[t * NBASES + 4 + b] * w;
            *(f32x4v*)&cS[node][slot][0] = c0;
            *(f32x4v*)&cS[node][slot][4] = c1;
            sS[node][slot] = (unsigned)s;
        }
    }

    f32x2v accA[NBASES], accB[NBASES];                 // ch 4hl..4hl+1, 4hl+2..+3
#pragma unroll
    for (int b = 0; b < NBASES; b++) { accA[b] = (f32x2v){0.f,0.f}; accB[b] = (f32x2v){0.f,0.f}; }

    if (alive) {
        for (int e0 = 0; e0 < ne; e0 += 16) {
            unsigned qd[16];
#pragma unroll
            for (int j = 0; j < 16; j++) {             // 16 gathers in flight
                unsigned s = sS[node][e0 + j];
                qd[j] = ((const unsigned*)(q8 + (size_t)s * 64))[hl];
            }
#pragma unroll
            for (int j = 0; j < 16; j++) {
                f32x4v ca = *(const f32x4v*)&cS[node][e0 + j][0];
                f32x4v cb = *(const f32x4v*)&cS[node][e0 + j][4];
                unsigned d = qd[j];
                f32x2v f01, f23;
                f01.x = (float)(char)(d & 0xff);
                f01.y = (float)(char)((d >> 8) & 0xff);
                f23.x = (float)(char)((d >> 16) & 0xff);
                f23.y = (float)(char)(d >> 24);
                accA[0] += ca[0] * f01;  accB[0] += ca[0] * f23;
                accA[1] += ca[1] * f01;  accB[1] += ca[1] * f23;
                accA[2] += ca[2] * f01;  accB[2] += ca[2] * f23;
                accA[3] += ca[3] * f01;  accB[3] += ca[3] * f23;
                accA[4] += cb[0] * f01;  accB[4] += cb[0] * f23;
                accA[5] += cb[1] * f01;  accB[5] += cb[1] * f23;
                accA[6] += cb[2] * f01;  accB[6] += cb[2] * f23;
                accA[7] += cb[3] * f01;  accB[7] += cb[3] * f23;
            }
        }
        __hip_bfloat16* Arow = A + (size_t)rl * KTOT;
#pragma unroll
        for (int b = 0; b < NBASES; b++) {             // one 8 B store: 4 bf16 ch
            bf16x4s o;
            o.lo.x = __float2bfloat16(accA[b].x);
            o.lo.y = __float2bfloat16(accA[b].y);
            o.hi.x = __float2bfloat16(accB[b].x);
            o.hi.y = __float2bfloat16(accB[b].y);
            *(bf16x4s*)&Arow[b * 128 + 4 * hl] = o;
        }
        *(bf16x4s*)&Arow[1024 + 4 * hl] =
            *(const bf16x4s*)&hin[(size_t)v * 128 + 4 * hl];   // root: own features
    }
}

// WT[o][k] (B^T, K-contiguous).
__global__ __launch_bounds__(256)
void k_w(const float* __restrict__ bases, const float* __restrict__ root,
         __hip_bfloat16* __restrict__ WT, int dout, int npad)
{
    int idx = blockIdx.x * 256 + threadIdx.x;
    int total = npad * KTOT;
    if (idx >= total) return;
    int o = idx / KTOT, k = idx - o * KTOT;
    float v = 0.f;
    if (o < dout) v = (k < 1024) ? bases[k * dout + o] : root[(k - 1024) * dout + o];
    WT[idx] = __float2bfloat16(v);
}

// C[M,NT] = A[M,K] * WT[NT,K]^T. 128x{128|64} tile, BK=32, 4 waves,
// mfma_f32_16x16x32_bf16, global_load_lds (width 16) staging.
template<int NT, bool RELU, bool FINAL>
__global__ __launch_bounds__(256)
void k_gemm(const __hip_bfloat16* __restrict__ A,
            const __hip_bfloat16* __restrict__ WT,
            const float* __restrict__ bias,
            void* __restrict__ outp,
            int r0, int rows, int dout)
{
    constexpr int WM = (NT == 128) ? 2 : 4;
    constexpr int WN = 4 / WM;
    constexpr int MT = 128 / (16 * WM);
    constexpr int NTW = NT / (16 * WN);
    __shared__ __align__(16) __hip_bfloat16 As[128 * 32];
    __shared__ __align__(16) __hip_bfloat16 Bs[NT * 32];
    int tid = threadIdx.x;
    int wave = tid >> 6, lane = tid & 63;
    int wm = wave % WM, wn = wave / WM;
    int bm = blockIdx.x * 128;
    int lm = lane & 15, lq = lane >> 4;
    f32x4v zero = {0.f, 0.f, 0.f, 0.f};
    f32x4v acc[MT][NTW];
#pragma unroll
    for (int a = 0; a < MT; a++)
#pragma unroll
        for (int b = 0; b < NTW; b++) acc[a][b] = zero;

    for (int k0 = 0; k0 < KTOT; k0 += 32) {
#pragma unroll
        for (int j = 0; j < 2; j++) {
            int slot = tid + 256 * j;
            int row = slot >> 2, kc = (slot & 3) << 3;
            __builtin_amdgcn_global_load_lds(
                (const __attribute__((address_space(1))) void*)
                    &A[(size_t)(bm + row) * KTOT + k0 + kc],
                (__attribute__((address_space(3))) void*)&As[slot * 8],
                16, 0, 0);
        }
#pragma unroll
        for (int j = 0; j < NT / 64; j++) {
            int slot = tid + 256 * j;
            int row = slot >> 2, kc = (slot & 3) << 3;
            __builtin_amdgcn_global_load_lds(
                (const __attribute__((address_space(1))) void*)
                    &WT[(size_t)row * KTOT + k0 + kc],
                (__attribute__((address_space(3))) void*)&Bs[slot * 8],
                16, 0, 0);
        }
        __syncthreads();
        bf16x8v af[MT], bfr[NTW];
#pragma unroll
        for (int mt = 0; mt < MT; mt++)
            af[mt] = *(const bf16x8v*)&As[(wm * (16 * MT) + mt * 16 + lm) * 32 + lq * 8];
#pragma unroll
        for (int nt = 0; nt < NTW; nt++)
            bfr[nt] = *(const bf16x8v*)&Bs[(wn * (16 * NTW) + nt * 16 + lm) * 32 + lq * 8];
#pragma unroll
        for (int mt = 0; mt < MT; mt++)
#pragma unroll
            for (int nt = 0; nt < NTW; nt++)
                acc[mt][nt] = __builtin_amdgcn_mfma_f32_16x16x32_bf16(
                    af[mt], bfr[nt], acc[mt][nt], 0, 0, 0);
        __syncthreads();
    }
#pragma unroll
    for (int mt = 0; mt < MT; mt++) {
        int rbase = bm + wm * (16 * MT) + mt * 16 + lq * 4;
#pragma unroll
        for (int nt = 0; nt < NTW; nt++) {
            int col = wn * (16 * NTW) + nt * 16 + lm;
#pragma unroll
            for (int i = 0; i < 4; i++) {
                int rl = rbase + i;
                if (rl < rows && col < dout) {
                    float v = acc[mt][nt][i] + bias[col];
                    if (RELU) v = fmaxf(v, 0.f);
                    if (FINAL)
                        ((float*)outp)[(size_t)(r0 + rl) * NCLS + col] = v;
                    else
                        ((__hip_bfloat16*)outp)[(size_t)(r0 + rl) * DFEAT + col] =
                            __float2bfloat16(v);
                }
            }
        }
    }
}

extern "C" void kernel_launch(void* const* d_in, const int* in_sizes, int n_in,
                              void* d_out, int out_size, void* d_ws, size_t ws_size,
                              hipStream_t stream)
{
    const float* x  = (const float*)d_in[0];
    const int* esrc = (const int*)d_in[1];
    const int* edst = (const int*)d_in[2];
    const int* etyp = (const int*)d_in[3];
    const float* basesA[3] = {(const float*)d_in[4], (const float*)d_in[8], (const float*)d_in[12]};
    const float* compA[3]  = {(const float*)d_in[5], (const float*)d_in[9], (const float*)d_in[13]};
    const float* rootA[3]  = {(const float*)d_in[6], (const float*)d_in[10], (const float*)d_in[14]};
    const float* biasA[3]  = {(const float*)d_in[7], (const float*)d_in[11], (const float*)d_in[15]};

    size_t off = 0;
    char* base = (char*)d_ws;
    auto carve = [&](size_t bytes) -> void* {
        void* r = base + off;
        off += (bytes + 255) & ~(size_t)255;
        return r;
    };
    __hip_bfloat16* xb = (__hip_bfloat16*)carve((size_t)NNODES * DFEAT * 2);
    __hip_bfloat16* h1 = (__hip_bfloat16*)carve((size_t)NNODES * DFEAT * 2);
    __hip_bfloat16* WT = (__hip_bfloat16*)carve((size_t)128 * KTOT * 2);
    unsigned* ell  = (unsigned*)carve((size_t)NNODES * MAXDEG * 4);
    unsigned* degD = (unsigned*)carve((size_t)NNODES * 4);
    short* q8  = (short*)carve((size_t)NNODES * 64 * 2);
    float* qsc = (float*)carve((size_t)NNODES * 4);
    __hip_bfloat16* h2 = xb;   // xb dead after layer 1 -> alias

    if (ws_size <= off) return;
    size_t arows = (ws_size - off) / ((size_t)KTOT * 2);
    if (arows > 100096) arows = 100096;        // max chunk (R6's small chunks regressed)
    int chunk = (int)(arows & ~(size_t)127);
    if (chunk < 128) return;
    __hip_bfloat16* A = (__hip_bfloat16*)(base + off);

    hipMemsetAsync(degD, 0, (size_t)NNODES * 4, stream);
    k_cvq<<<(NNODES + 3) / 4, 256, 0, stream>>>(x, xb, q8, qsc, NNODES);
    k_build<<<(NEDGES + 255) / 256, 256, 0, stream>>>(esrc, edst, etyp, degD, ell);

    const __hip_bfloat16* hin = xb;
    __hip_bfloat16* houts[2] = {h1, h2};
    for (int l = 0; l < 3; l++) {
        int dout = (l == 2) ? NCLS : DFEAT;
        int npad = (l == 2) ? 64 : 128;
        if (l > 0)   // layer 0's q8/qs came fused from k_cvq
            k_quant<<<(NNODES + 3) / 4, 256, 0, stream>>>(hin, q8, qsc, NNODES);
        k_w<<<(npad * KTOT + 255) / 256, 256, 0, stream>>>(basesA[l], rootA[l], WT, dout, npad);
        for (int r0 = 0; r0 < NNODES; r0 += chunk) {
            int rows = NNODES - r0; if (rows > chunk) rows = chunk;
            k_agg<<<(rows + 7) / 8, 256, 0, stream>>>(q8, qsc, hin, ell, degD, compA[l], A, r0, rows);
            int gm = (rows + 127) / 128;
            if (l < 2)
                k_gemm<128, true, false><<<gm, 256, 0, stream>>>(A, WT, biasA[l], houts[l], r0, rows, dout);
            else
                k_gemm<64, false, true><<<gm, 256, 0, stream>>>(A, WT, biasA[l], d_out, r0, rows, dout);
        }
        if (l < 2) hin = houts[l];
    }
}